// Round 6
// baseline (1032.040 us; speedup 1.0000x reference)
//
#include <hip/hip_runtime.h>

// Problem: B=4, S=2048, D=2048, H=16, KV=4, HD=128, NREP=4, causal attention.
// Pipeline: cast->GEMM1(qkv)->rope->flash-attn->GEMM2. All MFMA bf16 16x16x32.

typedef __bf16 bf16_t;
typedef __bf16 bf16x2 __attribute__((ext_vector_type(2)));
typedef __bf16 bf16x4 __attribute__((ext_vector_type(4)));
typedef short s16x8 __attribute__((ext_vector_type(8)));   // 8 bf16 payload (4 VGPRs)
typedef float f32x4 __attribute__((ext_vector_type(4)));
typedef unsigned int u32;
typedef unsigned short u16;

#define GLDS16(gp, lp)                                                        \
  __builtin_amdgcn_global_load_lds(                                           \
      (const __attribute__((address_space(1))) unsigned int*)(gp),            \
      (__attribute__((address_space(3))) unsigned int*)(lp), 16, 0, 0)

__device__ __forceinline__ f32x4 f4zero() {
  f32x4 z; z[0] = 0.f; z[1] = 0.f; z[2] = 0.f; z[3] = 0.f; return z;
}

// ---------------------------------------------------------------- cast f32->bf16
__global__ __launch_bounds__(256) void cast_bf16_k(
    const float* __restrict__ in, bf16_t* __restrict__ out, int n) {
  const int i = (blockIdx.x * 256 + threadIdx.x) * 4;
  if (i < n) {
    const float4 v = *(const float4*)(in + i);
    bf16x4 o;
    o[0] = (bf16_t)v.x; o[1] = (bf16_t)v.y; o[2] = (bf16_t)v.z; o[3] = (bf16_t)v.w;
    *(bf16x4*)(out + i) = o;
  }
}

// ---------------------------------------------------------------- RoPE (in-place on q,k of qkv)
// qkv rows: [B*S][3072]; q cols [0,2048) (16 heads), k cols [2048,2560) (4 heads).
// One wave per (row, head): lane l reads pair (2l,2l+1), writes real->l, imag->64+l
// (reference's concat layout). Wave-lockstep: 64-lane load completes before stores.
__global__ __launch_bounds__(256) void rope_k(
    bf16_t* __restrict__ qkv, const float* __restrict__ fc) {
  const int idx = blockIdx.x * 4 + (threadIdx.x >> 6);  // over 8192*20 row-heads
  const int l = threadIdx.x & 63;
  const int m = idx / 20;
  const int t = idx - m * 20;
  const int s = m & 2047;
  bf16_t* p = qkv + (size_t)m * 3072 + (t < 16 ? t * 128 : 2048 + (t - 16) * 128);
  const bf16x2 v = *(const bf16x2*)(p + 2 * l);
  const float2 cs = ((const float2*)fc)[s * 64 + l];
  const float x0 = (float)v[0], x1 = (float)v[1];
  const float re = x0 * cs.x - x1 * cs.y;
  const float im = x0 * cs.y + x1 * cs.x;
  p[l] = (bf16_t)re;
  p[64 + l] = (bf16_t)im;
}

// ---------------------------------------------------------------- GEMM  C[M][N] = A[M][K] @ B[N][K]^T
// m97 structure: 128x128 tile, BK=32, 4 waves (2x2 of 64x64), 4x4 16x16x32 frags,
// global_load_lds width-16, linear LDS, 2-barrier K-loop.
template <int F32OUT>
__global__ __launch_bounds__(256) void gemm_bt(
    const bf16_t* __restrict__ A, const bf16_t* __restrict__ B,
    float* __restrict__ Cf, bf16_t* __restrict__ Cb, int M, int N, int K) {
  __shared__ bf16_t lA[128 * 32];
  __shared__ bf16_t lB[128 * 32];
  const int tid = threadIdx.x;
  const int l = tid & 63, w = tid >> 6;
  const int fr = l & 15, fg = l >> 4;
  const int row0 = blockIdx.x * 128, col0 = blockIdx.y * 128;
  const int wm = (w >> 1) * 64, wn = (w & 1) * 64;
  const int sr = tid >> 2, sk = (tid & 3) * 8;  // staging: row tid/4, k (tid%4)*8

  const bf16_t* ga = A + (size_t)(row0 + sr) * K + sk;
  const bf16_t* gb = B + (size_t)(col0 + sr) * K + sk;
  bf16_t* la = lA + tid * 8;  // dest = wave-uniform base + lane*16B
  bf16_t* lb = lB + tid * 8;

  f32x4 acc[4][4];
#pragma unroll
  for (int mi = 0; mi < 4; ++mi)
#pragma unroll
    for (int ni = 0; ni < 4; ++ni) acc[mi][ni] = f4zero();

  for (int kt = 0; kt < K; kt += 32) {
    GLDS16(ga + kt, la);
    GLDS16(ga + (size_t)64 * K + kt, la + 2048);
    GLDS16(gb + kt, lb);
    GLDS16(gb + (size_t)64 * K + kt, lb + 2048);
    __syncthreads();  // compiler drains vmcnt before s_barrier

    s16x8 af[4], bfr[4];
#pragma unroll
    for (int mi = 0; mi < 4; ++mi)
      af[mi] = *(const s16x8*)&lA[(wm + mi * 16 + fr) * 32 + fg * 8];
#pragma unroll
    for (int ni = 0; ni < 4; ++ni)
      bfr[ni] = *(const s16x8*)&lB[(wn + ni * 16 + fr) * 32 + fg * 8];
#pragma unroll
    for (int mi = 0; mi < 4; ++mi)
#pragma unroll
      for (int ni = 0; ni < 4; ++ni)
        acc[mi][ni] = __builtin_amdgcn_mfma_f32_16x16x32_bf16(af[mi], bfr[ni], acc[mi][ni], 0, 0, 0);
    __syncthreads();
  }

#pragma unroll
  for (int mi = 0; mi < 4; ++mi)
#pragma unroll
    for (int ni = 0; ni < 4; ++ni)
#pragma unroll
      for (int r = 0; r < 4; ++r) {
        const int rr = row0 + wm + mi * 16 + fg * 4 + r;  // C: row=(l>>4)*4+reg
        const int cc = col0 + wn + ni * 16 + fr;          //    col=l&15
        if (F32OUT) Cf[(size_t)rr * N + cc] = acc[mi][ni][r];
        else        Cb[(size_t)rr * N + cc] = (bf16_t)acc[mi][ni][r];
      }
}

// ---------------------------------------------------------------- flash attention (causal, GQA)
// grid (S/128, H, B), 256 thr. Wave w owns q-rows [qb+32w, +32). KV tile = 64.
// K LDS [64][128] XOR-swizzled (d ^ (n&7)<<3); V transposed on stage into [128][72]
// swizzled (k ^ ((d>>3)&7)<<3); P per-wave [32][64] swizzled (k ^ (q&7)<<3).
__global__ __launch_bounds__(256) void attn_k(
    const bf16_t* __restrict__ qkv, bf16_t* __restrict__ o) {
  constexpr int S = 2048;
  constexpr float SCALE = 0.08838834764831845f;  // 1/sqrt(128)
  constexpr float L2E = 1.4426950408889634f;

  __shared__ bf16_t lK[64 * 128];
  __shared__ bf16_t lVT[128 * 72];
  __shared__ bf16_t lP[4][32 * 64];

  const int tid = threadIdx.x, l = tid & 63, w = tid >> 6;
  const int fr = l & 15, fg = l >> 4;
  const int qt = blockIdx.x, h = blockIdx.y, b = blockIdx.z;
  const int g = h >> 2;  // kv head
  const int qb = qt * 128;
  const int rowg0 = qb + w * 32;

  // Q fragments in registers (A-operand): row=fr, k = ks*32 + fg*8 (+e)
  s16x8 qf[2][4];
  {
    const bf16_t* qp = qkv + (size_t)(b * S + rowg0 + fr) * 3072 + h * 128 + fg * 8;
#pragma unroll
    for (int mi = 0; mi < 2; ++mi)
#pragma unroll
      for (int ks = 0; ks < 4; ++ks)
        qf[mi][ks] = *(const s16x8*)(qp + (size_t)mi * 16 * 3072 + ks * 32);
  }

  f32x4 oacc[2][8];
  float Mrow[2][4], Lrow[2][4];
#pragma unroll
  for (int mi = 0; mi < 2; ++mi) {
#pragma unroll
    for (int nd = 0; nd < 8; ++nd) oacc[mi][nd] = f4zero();
#pragma unroll
    for (int r = 0; r < 4; ++r) { Mrow[mi][r] = -1e30f; Lrow[mi][r] = 0.f; }
  }

  const int ktmax = qb / 64 + 1;
  const int kn = tid >> 4;          // 0..15 staging row group
  const int kd0 = (tid & 15) * 8;   // staging d offset
  const int swzv = (tid & 7) << 3;  // V swizzle = ((d>>3)&7)<<3 with d=kd0+j

  for (int kt = 0; kt <= ktmax; ++kt) {
    {  // ---- stage K tile (reg-staged, 16B loads, swizzled)
      const bf16_t* kg0 = qkv + (size_t)(b * S + kt * 64) * 3072 + 2048 + g * 128;
#pragma unroll
      for (int p = 0; p < 4; ++p) {
        const int n = kn + p * 16;
        const s16x8 v = *(const s16x8*)(kg0 + (size_t)n * 3072 + kd0);
        *(s16x8*)&lK[n * 128 + (kd0 ^ ((n & 7) << 3))] = v;
      }
      // ---- stage V transposed: VT[d][k], pairs packed as u32
      const bf16_t* vg0 = qkv + (size_t)(b * S + kt * 64) * 3072 + 2560 + g * 128;
#pragma unroll
      for (int p = 0; p < 2; ++p) {
        const int k2 = kn + p * 16;  // pair index: k = 2*k2, 2*k2+1
        const s16x8 va = *(const s16x8*)(vg0 + (size_t)(2 * k2) * 3072 + kd0);
        const s16x8 vb = *(const s16x8*)(vg0 + (size_t)(2 * k2 + 1) * 3072 + kd0);
#pragma unroll
        for (int j = 0; j < 8; ++j) {
          const u32 pr = (u32)(u16)va[j] | ((u32)(u16)vb[j] << 16);
          *(u32*)&lVT[(kd0 + j) * 72 + ((2 * k2) ^ swzv)] = pr;
        }
      }
    }
    __syncthreads();

    const bool skip = (kt * 64) > (rowg0 + 31);
    if (!skip) {
      // ---- S = Q K^T
      f32x4 sacc[2][4];
#pragma unroll
      for (int mi = 0; mi < 2; ++mi)
#pragma unroll
        for (int ni = 0; ni < 4; ++ni) sacc[mi][ni] = f4zero();
#pragma unroll
      for (int ks = 0; ks < 4; ++ks) {
        s16x8 kf[4];
#pragma unroll
        for (int ni = 0; ni < 4; ++ni) {
          const int n = ni * 16 + fr;
          kf[ni] = *(const s16x8*)&lK[n * 128 + ((ks * 32 + fg * 8) ^ ((n & 7) << 3))];
        }
#pragma unroll
        for (int mi = 0; mi < 2; ++mi)
#pragma unroll
          for (int ni = 0; ni < 4; ++ni)
            sacc[mi][ni] = __builtin_amdgcn_mfma_f32_16x16x32_bf16(qf[mi][ks], kf[ni], sacc[mi][ni], 0, 0, 0);
      }

      // ---- scale + causal mask
      const bool diag = (kt * 64 + 63) > rowg0;
#pragma unroll
      for (int mi = 0; mi < 2; ++mi)
#pragma unroll
        for (int ni = 0; ni < 4; ++ni)
#pragma unroll
          for (int r = 0; r < 4; ++r) {
            float v = sacc[mi][ni][r] * SCALE;
            if (diag) {
              const int qg = rowg0 + mi * 16 + fg * 4 + r;
              const int kg = kt * 64 + ni * 16 + fr;
              if (kg > qg) v = -1e30f;
            }
            sacc[mi][ni][r] = v;
          }

      // ---- online softmax (rows live in 16-lane groups: reduce over fr)
      bf16_t* lPw = &lP[w][0];
#pragma unroll
      for (int mi = 0; mi < 2; ++mi)
#pragma unroll
        for (int r = 0; r < 4; ++r) {
          float tm = fmaxf(fmaxf(sacc[mi][0][r], sacc[mi][1][r]),
                           fmaxf(sacc[mi][2][r], sacc[mi][3][r]));
#pragma unroll
          for (int d = 1; d < 16; d <<= 1) tm = fmaxf(tm, __shfl_xor(tm, d, 64));
          const float mOld = Mrow[mi][r];
          const float mNew = fmaxf(mOld, tm);
          const float alpha = exp2f((mOld - mNew) * L2E);
          float ps = 0.f;
#pragma unroll
          for (int ni = 0; ni < 4; ++ni) {
            const float p = exp2f((sacc[mi][ni][r] - mNew) * L2E);
            sacc[mi][ni][r] = p;
            ps += p;
          }
#pragma unroll
          for (int d = 1; d < 16; d <<= 1) ps += __shfl_xor(ps, d, 64);
          Lrow[mi][r] = Lrow[mi][r] * alpha + ps;
          Mrow[mi][r] = mNew;
#pragma unroll
          for (int nd = 0; nd < 8; ++nd) oacc[mi][nd][r] *= alpha;
        }

      // ---- P -> LDS (bf16, swizzled)
#pragma unroll
      for (int mi = 0; mi < 2; ++mi)
#pragma unroll
        for (int ni = 0; ni < 4; ++ni)
#pragma unroll
          for (int r = 0; r < 4; ++r) {
            const int ql = mi * 16 + fg * 4 + r;
            const int kl = ni * 16 + fr;
            lPw[ql * 64 + (kl ^ ((ql & 7) << 3))] = (bf16_t)sacc[mi][ni][r];
          }

      // ---- O += P V
#pragma unroll
      for (int ks2 = 0; ks2 < 2; ++ks2) {
        s16x8 pf[2];
#pragma unroll
        for (int mi = 0; mi < 2; ++mi) {
          const int q = mi * 16 + fr;
          pf[mi] = *(const s16x8*)&lPw[q * 64 + ((ks2 * 32 + fg * 8) ^ ((q & 7) << 3))];
        }
#pragma unroll
        for (int nd = 0; nd < 8; ++nd) {
          const int d = nd * 16 + fr;
          const s16x8 vf = *(const s16x8*)&lVT[d * 72 + ((ks2 * 32 + fg * 8) ^ (((d >> 3) & 7) << 3))];
#pragma unroll
          for (int mi = 0; mi < 2; ++mi)
            oacc[mi][nd] = __builtin_amdgcn_mfma_f32_16x16x32_bf16(pf[mi], vf, oacc[mi][nd], 0, 0, 0);
        }
      }
    }
    __syncthreads();
  }

  // ---- epilogue: normalize + store bf16
#pragma unroll
  for (int mi = 0; mi < 2; ++mi)
#pragma unroll
    for (int nd = 0; nd < 8; ++nd)
#pragma unroll
      for (int r = 0; r < 4; ++r) {
        const int rr = rowg0 + mi * 16 + fg * 4 + r;
        o[(size_t)(b * S + rr) * 2048 + h * 128 + nd * 16 + fr] =
            (bf16_t)(oacc[mi][nd][r] / Lrow[mi][r]);
      }
}

// ---------------------------------------------------------------- launcher
extern "C" void kernel_launch(void* const* d_in, const int* in_sizes, int n_in,
                              void* d_out, int out_size, void* d_ws, size_t ws_size,
                              hipStream_t stream) {
  (void)in_sizes; (void)n_in; (void)out_size; (void)ws_size;
  const float* x     = (const float*)d_in[0];
  const float* freqs = (const float*)d_in[1];
  // d_in[2] = mask: causal, computed analytically
  const float* wq = (const float*)d_in[3];
  const float* wk = (const float*)d_in[4];
  const float* wv = (const float*)d_in[5];
  const float* wo = (const float*)d_in[6];
  float* out = (float*)d_out;

  char* ws = (char*)d_ws;
  bf16_t* xb  = (bf16_t*)(ws);                  // [8192][2048]  33.55 MB
  bf16_t* Wb  = (bf16_t*)(ws + 33554432);       // [3072][2048]  12.58 MB
  bf16_t* wob = (bf16_t*)(ws + 46137344);       // [2048][2048]   8.39 MB
  bf16_t* qkv = (bf16_t*)(ws + 54525952);       // [8192][3072]  50.33 MB
  bf16_t* att = xb;                             // reuse x region after GEMM1

  // casts
  cast_bf16_k<<<16384, 256, 0, stream>>>(x, xb, 8192 * 2048);
  cast_bf16_k<<<4096, 256, 0, stream>>>(wq, Wb, 2048 * 2048);
  cast_bf16_k<<<1024, 256, 0, stream>>>(wk, Wb + 2048 * 2048, 512 * 2048);
  cast_bf16_k<<<1024, 256, 0, stream>>>(wv, Wb + 2560 * 2048, 512 * 2048);
  cast_bf16_k<<<4096, 256, 0, stream>>>(wo, wob, 2048 * 2048);

  // qkv = xb @ Wb^T  (M=8192, N=3072, K=2048), bf16 out
  gemm_bt<0><<<dim3(64, 24), 256, 0, stream>>>(xb, Wb, nullptr, qkv, 8192, 3072, 2048);

  // rope on q,k heads in-place: 8192 rows * 20 heads, 4 rows/block
  rope_k<<<40960, 256, 0, stream>>>(qkv, freqs);

  // attention -> att [8192][2048] bf16
  attn_k<<<dim3(16, 16, 4), 256, 0, stream>>>(qkv, att);

  // out = att @ wob^T (M=8192, N=2048, K=2048), fp32 out
  gemm_bt<1><<<dim3(64, 16), 256, 0, stream>>>(att, wob, out, nullptr, 8192, 2048, 2048);
}

// Round 7
// 944.572 us; speedup vs baseline: 1.0926x; 1.0926x over previous
//
#include <hip/hip_runtime.h>

// Problem: B=4, S=2048, D=2048, H=16, KV=4, HD=128, NREP=4, causal attention.
// Pipeline: cast->GEMM1(qkv)->rope->flash-attn->GEMM2. All MFMA bf16 16x16x32.

typedef __bf16 bf16_t;
typedef __bf16 bf16x2 __attribute__((ext_vector_type(2)));
typedef __bf16 bf16x4 __attribute__((ext_vector_type(4)));
typedef short s16x8 __attribute__((ext_vector_type(8)));   // 8 bf16 payload (4 VGPRs)
typedef float f32x4 __attribute__((ext_vector_type(4)));
typedef unsigned int u32;
typedef unsigned short u16;

#define GLDS16(gp, lp)                                                        \
  __builtin_amdgcn_global_load_lds(                                           \
      (const __attribute__((address_space(1))) unsigned int*)(gp),            \
      (__attribute__((address_space(3))) unsigned int*)(lp), 16, 0, 0)

__device__ __forceinline__ f32x4 f4zero() {
  f32x4 z; z[0] = 0.f; z[1] = 0.f; z[2] = 0.f; z[3] = 0.f; return z;
}

// ---------------------------------------------------------------- cast f32->bf16
__global__ __launch_bounds__(256) void cast_bf16_k(
    const float* __restrict__ in, bf16_t* __restrict__ out, int n) {
  const int i = (blockIdx.x * 256 + threadIdx.x) * 4;
  if (i < n) {
    const float4 v = *(const float4*)(in + i);
    bf16x4 o;
    o[0] = (bf16_t)v.x; o[1] = (bf16_t)v.y; o[2] = (bf16_t)v.z; o[3] = (bf16_t)v.w;
    *(bf16x4*)(out + i) = o;
  }
}

// ---------------------------------------------------------------- RoPE (in-place on q,k of qkv)
__global__ __launch_bounds__(256) void rope_k(
    bf16_t* __restrict__ qkv, const float* __restrict__ fc) {
  const int idx = blockIdx.x * 4 + (threadIdx.x >> 6);  // over 8192*20 row-heads
  const int l = threadIdx.x & 63;
  const int m = idx / 20;
  const int t = idx - m * 20;
  const int s = m & 2047;
  bf16_t* p = qkv + (size_t)m * 3072 + (t < 16 ? t * 128 : 2048 + (t - 16) * 128);
  const bf16x2 v = *(const bf16x2*)(p + 2 * l);
  const float2 cs = ((const float2*)fc)[s * 64 + l];
  const float x0 = (float)v[0], x1 = (float)v[1];
  const float re = x0 * cs.x - x1 * cs.y;
  const float im = x0 * cs.y + x1 * cs.x;
  p[l] = (bf16_t)re;
  p[64 + l] = (bf16_t)im;
}

// ---------------------------------------------------------------- GEMM  C[M][N] = A[M][K] @ B[N][K]^T
template <int F32OUT>
__global__ __launch_bounds__(256) void gemm_bt(
    const bf16_t* __restrict__ A, const bf16_t* __restrict__ B,
    float* __restrict__ Cf, bf16_t* __restrict__ Cb, int M, int N, int K) {
  __shared__ bf16_t lA[128 * 32];
  __shared__ bf16_t lB[128 * 32];
  const int tid = threadIdx.x;
  const int l = tid & 63, w = tid >> 6;
  const int fr = l & 15, fg = l >> 4;
  const int row0 = blockIdx.x * 128, col0 = blockIdx.y * 128;
  const int wm = (w >> 1) * 64, wn = (w & 1) * 64;
  const int sr = tid >> 2, sk = (tid & 3) * 8;

  const bf16_t* ga = A + (size_t)(row0 + sr) * K + sk;
  const bf16_t* gb = B + (size_t)(col0 + sr) * K + sk;
  bf16_t* la = lA + tid * 8;
  bf16_t* lb = lB + tid * 8;

  f32x4 acc[4][4];
#pragma unroll
  for (int mi = 0; mi < 4; ++mi)
#pragma unroll
    for (int ni = 0; ni < 4; ++ni) acc[mi][ni] = f4zero();

  for (int kt = 0; kt < K; kt += 32) {
    GLDS16(ga + kt, la);
    GLDS16(ga + (size_t)64 * K + kt, la + 2048);
    GLDS16(gb + kt, lb);
    GLDS16(gb + (size_t)64 * K + kt, lb + 2048);
    __syncthreads();

    s16x8 af[4], bfr[4];
#pragma unroll
    for (int mi = 0; mi < 4; ++mi)
      af[mi] = *(const s16x8*)&lA[(wm + mi * 16 + fr) * 32 + fg * 8];
#pragma unroll
    for (int ni = 0; ni < 4; ++ni)
      bfr[ni] = *(const s16x8*)&lB[(wn + ni * 16 + fr) * 32 + fg * 8];
#pragma unroll
    for (int mi = 0; mi < 4; ++mi)
#pragma unroll
      for (int ni = 0; ni < 4; ++ni)
        acc[mi][ni] = __builtin_amdgcn_mfma_f32_16x16x32_bf16(af[mi], bfr[ni], acc[mi][ni], 0, 0, 0);
    __syncthreads();
  }

#pragma unroll
  for (int mi = 0; mi < 4; ++mi)
#pragma unroll
    for (int ni = 0; ni < 4; ++ni)
#pragma unroll
      for (int r = 0; r < 4; ++r) {
        const int rr = row0 + wm + mi * 16 + fg * 4 + r;
        const int cc = col0 + wn + ni * 16 + fr;
        if (F32OUT) Cf[(size_t)rr * N + cc] = acc[mi][ni][r];
        else        Cb[(size_t)rr * N + cc] = (bf16_t)acc[mi][ni][r];
      }
}

// ---------------------------------------------------------------- flash attention (causal, GQA)
// 1-D grid 1024 blocks, XCD-chunked: id=(orig%8)*128+orig/8 -> each XCD owns 2
// (b,g) KV-sets (2MB, L2-resident). 256 thr, wave w owns q-rows [qb+32w,+32).
// K: fragments loaded DIRECTLY from global (L2-hot, no LDS). V: double-buffered
// LDS transpose [2][128][72] swizzled; ONE barrier per kv-tile iteration.
// V(t+1) loads issued right after barrier (latency hides under QK^T+softmax),
// written to buf^1 after softmax. P per-wave LDS [32][64] swizzled.
__global__ __launch_bounds__(256) void attn_k(
    const bf16_t* __restrict__ qkv, bf16_t* __restrict__ o) {
  constexpr int S = 2048;
  constexpr float SCALE = 0.08838834764831845f;  // 1/sqrt(128)
  constexpr float L2E = 1.4426950408889634f;
  constexpr float C1 = SCALE * L2E;              // fold scale into exp2

  __shared__ bf16_t lVT[2][128 * 72];
  __shared__ bf16_t lP[4][32 * 64];

  const int tid = threadIdx.x, l = tid & 63, w = tid >> 6;
  const int fr = l & 15, fg = l >> 4;
  const int orig = blockIdx.x;
  const int id = (orig & 7) * 128 + (orig >> 3);  // XCD-chunked remap
  const int qt = id & 15, h = (id >> 4) & 15, b = id >> 8;
  const int g = h >> 2;  // kv head
  const int qb = qt * 128;
  const int rowg0 = qb + w * 32;

  // Q fragments in registers (A-operand): row=fr, k = ks*32 + fg*8 (+e)
  s16x8 qf[2][4];
  {
    const bf16_t* qp = qkv + (size_t)(b * S + rowg0 + fr) * 3072 + h * 128 + fg * 8;
#pragma unroll
    for (int mi = 0; mi < 2; ++mi)
#pragma unroll
      for (int ks = 0; ks < 4; ++ks)
        qf[mi][ks] = *(const s16x8*)(qp + (size_t)mi * 16 * 3072 + ks * 32);
  }

  f32x4 oacc[2][8];
  float Mrow[2][4], Lrow[2][4];
#pragma unroll
  for (int mi = 0; mi < 2; ++mi) {
#pragma unroll
    for (int nd = 0; nd < 8; ++nd) oacc[mi][nd] = f4zero();
#pragma unroll
    for (int r = 0; r < 4; ++r) { Mrow[mi][r] = -1e30f; Lrow[mi][r] = 0.f; }
  }

  const int ktmax = qb / 64 + 1;
  const int kn = tid >> 4;          // 0..15 staging row group
  const int kd0 = (tid & 15) * 8;   // staging d offset
  const int swzv = (tid & 7) << 3;  // V swizzle = ((d>>3)&7)<<3 with d=kd0+j
  const int c0 = (2 * kn) ^ swzv;          // VT col, pair block p=0
  const int c1 = (2 * (kn + 16)) ^ swzv;   // VT col, pair block p=1

  // K per-lane base (row added per fragment): col offset fg*8 folded in.
  const bf16_t* kB = qkv + (size_t)(b * S) * 3072 + 2048 + g * 128 + fg * 8;
  // V per-lane base: col offset kd0 folded in.
  const bf16_t* vB = qkv + (size_t)(b * S) * 3072 + 2560 + g * 128 + kd0;

  s16x8 sva0, svb0, sva1, svb1;  // in-flight V tile (issue-early / write-late)

  // ---- prologue: stage V(0) into buf 0
  {
    const bf16_t* vg = vB;  // kt = 0
    sva0 = *(const s16x8*)(vg + (size_t)(2 * kn) * 3072);
    svb0 = *(const s16x8*)(vg + (size_t)(2 * kn + 1) * 3072);
    sva1 = *(const s16x8*)(vg + (size_t)(2 * (kn + 16)) * 3072);
    svb1 = *(const s16x8*)(vg + (size_t)(2 * (kn + 16) + 1) * 3072);
    bf16_t* vt = &lVT[0][0];
#pragma unroll
    for (int j = 0; j < 8; ++j) {
      *(u32*)&vt[(kd0 + j) * 72 + c0] = (u32)(u16)sva0[j] | ((u32)(u16)svb0[j] << 16);
      *(u32*)&vt[(kd0 + j) * 72 + c1] = (u32)(u16)sva1[j] | ((u32)(u16)svb1[j] << 16);
    }
  }

  for (int kt = 0; kt <= ktmax; ++kt) {
    __syncthreads();  // buf[kt&1] fully written; buf[(kt+1)&1] free for writes

    // ---- issue V(kt+1) loads (latency hides under QK^T + softmax)
    if (kt < ktmax) {
      const bf16_t* vg = vB + (size_t)((kt + 1) * 64) * 3072;
      sva0 = *(const s16x8*)(vg + (size_t)(2 * kn) * 3072);
      svb0 = *(const s16x8*)(vg + (size_t)(2 * kn + 1) * 3072);
      sva1 = *(const s16x8*)(vg + (size_t)(2 * (kn + 16)) * 3072);
      svb1 = *(const s16x8*)(vg + (size_t)(2 * (kn + 16) + 1) * 3072);
    }

    const bool skip = (kt * 64) > (rowg0 + 31);
    f32x4 sacc[2][4];
    if (!skip) {
      // ---- S = Q K^T, K fragments straight from global (L2-hot)
#pragma unroll
      for (int mi = 0; mi < 2; ++mi)
#pragma unroll
        for (int ni = 0; ni < 4; ++ni) sacc[mi][ni] = f4zero();
#pragma unroll
      for (int ks = 0; ks < 4; ++ks) {
        s16x8 kf[4];
#pragma unroll
        for (int ni = 0; ni < 4; ++ni)
          kf[ni] = *(const s16x8*)(kB + (size_t)(kt * 64 + ni * 16 + fr) * 3072 + ks * 32);
#pragma unroll
        for (int mi = 0; mi < 2; ++mi)
#pragma unroll
          for (int ni = 0; ni < 4; ++ni)
            sacc[mi][ni] = __builtin_amdgcn_mfma_f32_16x16x32_bf16(qf[mi][ks], kf[ni], sacc[mi][ni], 0, 0, 0);
      }

      // ---- causal mask (raw scores; scale folded into exp2 below)
      const bool diag = (kt * 64 + 63) > rowg0;
      if (diag) {
#pragma unroll
        for (int mi = 0; mi < 2; ++mi)
#pragma unroll
          for (int ni = 0; ni < 4; ++ni)
#pragma unroll
            for (int r = 0; r < 4; ++r) {
              const int qg = rowg0 + mi * 16 + fg * 4 + r;
              const int kg = kt * 64 + ni * 16 + fr;
              if (kg > qg) sacc[mi][ni][r] = -1e30f;
            }
      }

      // ---- online softmax (rows live in 16-lane groups: reduce over fr)
#pragma unroll
      for (int mi = 0; mi < 2; ++mi)
#pragma unroll
        for (int r = 0; r < 4; ++r) {
          float tm = fmaxf(fmaxf(sacc[mi][0][r], sacc[mi][1][r]),
                           fmaxf(sacc[mi][2][r], sacc[mi][3][r]));
#pragma unroll
          for (int d = 1; d < 16; d <<= 1) tm = fmaxf(tm, __shfl_xor(tm, d, 64));
          const float mOld = Mrow[mi][r];
          const float mNew = fmaxf(mOld, tm);
          const float alpha = exp2f((mOld - mNew) * C1);
          float ps = 0.f;
#pragma unroll
          for (int ni = 0; ni < 4; ++ni) {
            const float p = exp2f((sacc[mi][ni][r] - mNew) * C1);
            sacc[mi][ni][r] = p;
            ps += p;
          }
#pragma unroll
          for (int d = 1; d < 16; d <<= 1) ps += __shfl_xor(ps, d, 64);
          Lrow[mi][r] = Lrow[mi][r] * alpha + ps;
          Mrow[mi][r] = mNew;
#pragma unroll
          for (int nd = 0; nd < 8; ++nd) oacc[mi][nd][r] *= alpha;
        }
    }

    // ---- write V(kt+1) into buf^1 (all threads; vmcnt waits here, not earlier)
    if (kt < ktmax) {
      bf16_t* vt = &lVT[(kt + 1) & 1][0];
#pragma unroll
      for (int j = 0; j < 8; ++j) {
        *(u32*)&vt[(kd0 + j) * 72 + c0] = (u32)(u16)sva0[j] | ((u32)(u16)svb0[j] << 16);
        *(u32*)&vt[(kd0 + j) * 72 + c1] = (u32)(u16)sva1[j] | ((u32)(u16)svb1[j] << 16);
      }
    }

    if (!skip) {
      // ---- P -> per-wave LDS (bf16, swizzled)
      bf16_t* lPw = &lP[w][0];
#pragma unroll
      for (int mi = 0; mi < 2; ++mi)
#pragma unroll
        for (int ni = 0; ni < 4; ++ni)
#pragma unroll
          for (int r = 0; r < 4; ++r) {
            const int ql = mi * 16 + fg * 4 + r;
            const int kl = ni * 16 + fr;
            lPw[ql * 64 + (kl ^ ((ql & 7) << 3))] = (bf16_t)sacc[mi][ni][r];
          }

      // ---- O += P V from buf[kt&1]
      const bf16_t* vt = &lVT[kt & 1][0];
#pragma unroll
      for (int ks2 = 0; ks2 < 2; ++ks2) {
        s16x8 pf[2];
#pragma unroll
        for (int mi = 0; mi < 2; ++mi) {
          const int q = mi * 16 + fr;
          pf[mi] = *(const s16x8*)&lPw[q * 64 + ((ks2 * 32 + fg * 8) ^ ((q & 7) << 3))];
        }
#pragma unroll
        for (int nd = 0; nd < 8; ++nd) {
          const int d = nd * 16 + fr;
          const s16x8 vf = *(const s16x8*)&vt[d * 72 + ((ks2 * 32 + fg * 8) ^ (((d >> 3) & 7) << 3))];
#pragma unroll
          for (int mi = 0; mi < 2; ++mi)
            oacc[mi][nd] = __builtin_amdgcn_mfma_f32_16x16x32_bf16(pf[mi], vf, oacc[mi][nd], 0, 0, 0);
        }
      }
    }
  }

  // ---- epilogue: normalize + store bf16
#pragma unroll
  for (int mi = 0; mi < 2; ++mi)
#pragma unroll
    for (int nd = 0; nd < 8; ++nd)
#pragma unroll
      for (int r = 0; r < 4; ++r) {
        const int rr = rowg0 + mi * 16 + fg * 4 + r;
        o[(size_t)(b * S + rr) * 2048 + h * 128 + nd * 16 + fr] =
            (bf16_t)(oacc[mi][nd][r] / Lrow[mi][r]);
      }
}

// ---------------------------------------------------------------- launcher
extern "C" void kernel_launch(void* const* d_in, const int* in_sizes, int n_in,
                              void* d_out, int out_size, void* d_ws, size_t ws_size,
                              hipStream_t stream) {
  (void)in_sizes; (void)n_in; (void)out_size; (void)ws_size;
  const float* x     = (const float*)d_in[0];
  const float* freqs = (const float*)d_in[1];
  // d_in[2] = mask: causal, computed analytically
  const float* wq = (const float*)d_in[3];
  const float* wk = (const float*)d_in[4];
  const float* wv = (const float*)d_in[5];
  const float* wo = (const float*)d_in[6];
  float* out = (float*)d_out;

  char* ws = (char*)d_ws;
  bf16_t* xb  = (bf16_t*)(ws);                  // [8192][2048]  33.55 MB
  bf16_t* Wb  = (bf16_t*)(ws + 33554432);       // [3072][2048]  12.58 MB
  bf16_t* wob = (bf16_t*)(ws + 46137344);       // [2048][2048]   8.39 MB
  bf16_t* qkv = (bf16_t*)(ws + 54525952);       // [8192][3072]  50.33 MB
  bf16_t* att = xb;                             // reuse x region after GEMM1

  // casts
  cast_bf16_k<<<16384, 256, 0, stream>>>(x, xb, 8192 * 2048);
  cast_bf16_k<<<4096, 256, 0, stream>>>(wq, Wb, 2048 * 2048);
  cast_bf16_k<<<1024, 256, 0, stream>>>(wk, Wb + 2048 * 2048, 512 * 2048);
  cast_bf16_k<<<1024, 256, 0, stream>>>(wv, Wb + 2560 * 2048, 512 * 2048);
  cast_bf16_k<<<4096, 256, 0, stream>>>(wo, wob, 2048 * 2048);

  // qkv = xb @ Wb^T  (M=8192, N=3072, K=2048), bf16 out
  gemm_bt<0><<<dim3(64, 24), 256, 0, stream>>>(xb, Wb, nullptr, qkv, 8192, 3072, 2048);

  // rope on q,k heads in-place: 8192 rows * 20 heads, 4 rows/block
  rope_k<<<40960, 256, 0, stream>>>(qkv, freqs);

  // attention -> att [8192][2048] bf16 (1-D grid, XCD-chunked)
  attn_k<<<1024, 256, 0, stream>>>(qkv, att);

  // out = att @ wob^T (M=8192, N=2048, K=2048), fp32 out
  gemm_bt<1><<<dim3(64, 16), 256, 0, stream>>>(att, wob, out, nullptr, 8192, 2048, 2048);
}

// Round 10
// 795.440 us; speedup vs baseline: 1.2974x; 1.1875x over previous
//
#include <hip/hip_runtime.h>

// Problem: B=4, S=2048, D=2048, H=16, KV=4, HD=128, NREP=4, causal attention.
// Pipeline: cast->GEMM1(qkv)->rope->flash-attn->GEMM2. All MFMA bf16 16x16x32.

typedef __bf16 bf16_t;
typedef __bf16 bf16x2 __attribute__((ext_vector_type(2)));
typedef __bf16 bf16x4 __attribute__((ext_vector_type(4)));
typedef short s16x8 __attribute__((ext_vector_type(8)));   // 8 bf16 payload (4 VGPRs)
typedef float f32x4 __attribute__((ext_vector_type(4)));
typedef unsigned int u32;
typedef unsigned short u16;

#define GLDS16(gp, lp)                                                        \
  __builtin_amdgcn_global_load_lds(                                           \
      (const __attribute__((address_space(1))) unsigned int*)(gp),            \
      (__attribute__((address_space(3))) unsigned int*)(lp), 16, 0, 0)

__device__ __forceinline__ f32x4 f4zero() {
  f32x4 z; z[0] = 0.f; z[1] = 0.f; z[2] = 0.f; z[3] = 0.f; return z;
}

// ---------------------------------------------------------------- cast f32->bf16
__global__ __launch_bounds__(256) void cast_bf16_k(
    const float* __restrict__ in, bf16_t* __restrict__ out, int n) {
  const int i = (blockIdx.x * 256 + threadIdx.x) * 4;
  if (i < n) {
    const float4 v = *(const float4*)(in + i);
    bf16x4 o;
    o[0] = (bf16_t)v.x; o[1] = (bf16_t)v.y; o[2] = (bf16_t)v.z; o[3] = (bf16_t)v.w;
    *(bf16x4*)(out + i) = o;
  }
}

// ---------------------------------------------------------------- RoPE (in-place on q,k of qkv)
__global__ __launch_bounds__(256) void rope_k(
    bf16_t* __restrict__ qkv, const float* __restrict__ fc) {
  const int idx = blockIdx.x * 4 + (threadIdx.x >> 6);  // over 8192*20 row-heads
  const int l = threadIdx.x & 63;
  const int m = idx / 20;
  const int t = idx - m * 20;
  const int s = m & 2047;
  bf16_t* p = qkv + (size_t)m * 3072 + (t < 16 ? t * 128 : 2048 + (t - 16) * 128);
  const bf16x2 v = *(const bf16x2*)(p + 2 * l);
  const float2 cs = ((const float2*)fc)[s * 64 + l];
  const float x0 = (float)v[0], x1 = (float)v[1];
  const float re = x0 * cs.x - x1 * cs.y;
  const float im = x0 * cs.y + x1 * cs.x;
  p[l] = (bf16_t)re;
  p[64 + l] = (bf16_t)im;
}

// ---------------------------------------------------------------- GEMM  C[M][N] = A[M][K] @ B[N][K]^T
template <int F32OUT>
__global__ __launch_bounds__(256) void gemm_bt(
    const bf16_t* __restrict__ A, const bf16_t* __restrict__ B,
    float* __restrict__ Cf, bf16_t* __restrict__ Cb, int M, int N, int K) {
  __shared__ bf16_t lA[128 * 32];
  __shared__ bf16_t lB[128 * 32];
  const int tid = threadIdx.x;
  const int l = tid & 63, w = tid >> 6;
  const int fr = l & 15, fg = l >> 4;
  const int row0 = blockIdx.x * 128, col0 = blockIdx.y * 128;
  const int wm = (w >> 1) * 64, wn = (w & 1) * 64;
  const int sr = tid >> 2, sk = (tid & 3) * 8;

  const bf16_t* ga = A + (size_t)(row0 + sr) * K + sk;
  const bf16_t* gb = B + (size_t)(col0 + sr) * K + sk;
  bf16_t* la = lA + tid * 8;
  bf16_t* lb = lB + tid * 8;

  f32x4 acc[4][4];
#pragma unroll
  for (int mi = 0; mi < 4; ++mi)
#pragma unroll
    for (int ni = 0; ni < 4; ++ni) acc[mi][ni] = f4zero();

  for (int kt = 0; kt < K; kt += 32) {
    GLDS16(ga + kt, la);
    GLDS16(ga + (size_t)64 * K + kt, la + 2048);
    GLDS16(gb + kt, lb);
    GLDS16(gb + (size_t)64 * K + kt, lb + 2048);
    __syncthreads();

    s16x8 af[4], bfr[4];
#pragma unroll
    for (int mi = 0; mi < 4; ++mi)
      af[mi] = *(const s16x8*)&lA[(wm + mi * 16 + fr) * 32 + fg * 8];
#pragma unroll
    for (int ni = 0; ni < 4; ++ni)
      bfr[ni] = *(const s16x8*)&lB[(wn + ni * 16 + fr) * 32 + fg * 8];
#pragma unroll
    for (int mi = 0; mi < 4; ++mi)
#pragma unroll
      for (int ni = 0; ni < 4; ++ni)
        acc[mi][ni] = __builtin_amdgcn_mfma_f32_16x16x32_bf16(af[mi], bfr[ni], acc[mi][ni], 0, 0, 0);
    __syncthreads();
  }

#pragma unroll
  for (int mi = 0; mi < 4; ++mi)
#pragma unroll
    for (int ni = 0; ni < 4; ++ni)
#pragma unroll
      for (int r = 0; r < 4; ++r) {
        const int rr = row0 + wm + mi * 16 + fg * 4 + r;
        const int cc = col0 + wn + ni * 16 + fr;
        if (F32OUT) Cf[(size_t)rr * N + cc] = acc[mi][ni][r];
        else        Cb[(size_t)rr * N + cc] = (bf16_t)acc[mi][ni][r];
      }
}

// ---------------------------------------------------------------- flash attention (causal, GQA)
// 1-D grid 1024 blocks. Decode gives: (a) XCD-chunked KV locality (each XCD
// owns 8 (b,h) groups = 2 MB KV, L2-resident) and (b) LPT scheduling: within
// each XCD, all qt=15 blocks (33 kv-tiles) dispatch first, then qt=14, ...
// so the long blocks start immediately and short ones backfill the tail.
// 256 thr, wave w owns q-rows [qb+32w,+32). K fragments direct from global
// (L2-hot). V double-buffered LDS transpose [2][128][72] swizzled; ONE
// barrier per kv-tile; V(t+1) issue-early/write-late. P per-wave [32][64].
__global__ __launch_bounds__(256) void attn_k(
    const bf16_t* __restrict__ qkv, bf16_t* __restrict__ o) {
  constexpr int S = 2048;
  constexpr float SCALE = 0.08838834764831845f;  // 1/sqrt(128)
  constexpr float L2E = 1.4426950408889634f;
  constexpr float C1 = SCALE * L2E;              // fold scale into exp2

  __shared__ bf16_t lVT[2][128 * 72];
  __shared__ bf16_t lP[4][32 * 64];

  const int tid = threadIdx.x, l = tid & 63, w = tid >> 6;
  const int fr = l & 15, fg = l >> 4;
  const int orig = blockIdx.x;
  const int xcd = orig & 7;           // blocks round-robin across 8 XCDs
  const int seq = orig >> 3;          // dispatch sequence within XCD [0,128)
  const int qt = 15 - (seq >> 3);     // LPT: largest q-tile first
  const int grp = xcd * 8 + (seq & 7);// 8 (b,h) groups per XCD
  const int h = grp & 15, b = grp >> 4;
  const int g = h >> 2;  // kv head
  const int qb = qt * 128;
  const int rowg0 = qb + w * 32;

  // Q fragments in registers (A-operand): row=fr, k = ks*32 + fg*8 (+e)
  s16x8 qf[2][4];
  {
    const bf16_t* qp = qkv + (size_t)(b * S + rowg0 + fr) * 3072 + h * 128 + fg * 8;
#pragma unroll
    for (int mi = 0; mi < 2; ++mi)
#pragma unroll
      for (int ks = 0; ks < 4; ++ks)
        qf[mi][ks] = *(const s16x8*)(qp + (size_t)mi * 16 * 3072 + ks * 32);
  }

  f32x4 oacc[2][8];
  float Mrow[2][4], Lrow[2][4];
#pragma unroll
  for (int mi = 0; mi < 2; ++mi) {
#pragma unroll
    for (int nd = 0; nd < 8; ++nd) oacc[mi][nd] = f4zero();
#pragma unroll
    for (int r = 0; r < 4; ++r) { Mrow[mi][r] = -1e30f; Lrow[mi][r] = 0.f; }
  }

  const int ktmax = qb / 64 + 1;
  const int kn = tid >> 4;          // 0..15 staging row group
  const int kd0 = (tid & 15) * 8;   // staging d offset
  const int swzv = (tid & 7) << 3;  // V swizzle = ((d>>3)&7)<<3 with d=kd0+j
  const int c0 = (2 * kn) ^ swzv;          // VT col, pair block p=0
  const int c1 = (2 * (kn + 16)) ^ swzv;   // VT col, pair block p=1

  // K per-lane base (row added per fragment): col offset fg*8 folded in.
  const bf16_t* kB = qkv + (size_t)(b * S) * 3072 + 2048 + g * 128 + fg * 8;
  // V per-lane base: col offset kd0 folded in.
  const bf16_t* vB = qkv + (size_t)(b * S) * 3072 + 2560 + g * 128 + kd0;

  s16x8 sva0, svb0, sva1, svb1;  // in-flight V tile (issue-early / write-late)

  // ---- prologue: stage V(0) into buf 0
  {
    const bf16_t* vg = vB;  // kt = 0
    sva0 = *(const s16x8*)(vg + (size_t)(2 * kn) * 3072);
    svb0 = *(const s16x8*)(vg + (size_t)(2 * kn + 1) * 3072);
    sva1 = *(const s16x8*)(vg + (size_t)(2 * (kn + 16)) * 3072);
    svb1 = *(const s16x8*)(vg + (size_t)(2 * (kn + 16) + 1) * 3072);
    bf16_t* vt = &lVT[0][0];
#pragma unroll
    for (int j = 0; j < 8; ++j) {
      *(u32*)&vt[(kd0 + j) * 72 + c0] = (u32)(u16)sva0[j] | ((u32)(u16)svb0[j] << 16);
      *(u32*)&vt[(kd0 + j) * 72 + c1] = (u32)(u16)sva1[j] | ((u32)(u16)svb1[j] << 16);
    }
  }

  for (int kt = 0; kt <= ktmax; ++kt) {
    __syncthreads();  // buf[kt&1] fully written; buf[(kt+1)&1] free for writes

    // ---- issue V(kt+1) loads (latency hides under QK^T + softmax)
    if (kt < ktmax) {
      const bf16_t* vg = vB + (size_t)((kt + 1) * 64) * 3072;
      sva0 = *(const s16x8*)(vg + (size_t)(2 * kn) * 3072);
      svb0 = *(const s16x8*)(vg + (size_t)(2 * kn + 1) * 3072);
      sva1 = *(const s16x8*)(vg + (size_t)(2 * (kn + 16)) * 3072);
      svb1 = *(const s16x8*)(vg + (size_t)(2 * (kn + 16) + 1) * 3072);
    }

    const bool skip = (kt * 64) > (rowg0 + 31);
    f32x4 sacc[2][4];
    if (!skip) {
      // ---- S = Q K^T, K fragments straight from global (L2-hot)
#pragma unroll
      for (int mi = 0; mi < 2; ++mi)
#pragma unroll
        for (int ni = 0; ni < 4; ++ni) sacc[mi][ni] = f4zero();
#pragma unroll
      for (int ks = 0; ks < 4; ++ks) {
        s16x8 kf[4];
#pragma unroll
        for (int ni = 0; ni < 4; ++ni)
          kf[ni] = *(const s16x8*)(kB + (size_t)(kt * 64 + ni * 16 + fr) * 3072 + ks * 32);
#pragma unroll
        for (int mi = 0; mi < 2; ++mi)
#pragma unroll
          for (int ni = 0; ni < 4; ++ni)
            sacc[mi][ni] = __builtin_amdgcn_mfma_f32_16x16x32_bf16(qf[mi][ks], kf[ni], sacc[mi][ni], 0, 0, 0);
      }

      // ---- causal mask (raw scores; scale folded into exp2 below)
      const bool diag = (kt * 64 + 63) > rowg0;
      if (diag) {
#pragma unroll
        for (int mi = 0; mi < 2; ++mi)
#pragma unroll
          for (int ni = 0; ni < 4; ++ni)
#pragma unroll
            for (int r = 0; r < 4; ++r) {
              const int qg = rowg0 + mi * 16 + fg * 4 + r;
              const int kg = kt * 64 + ni * 16 + fr;
              if (kg > qg) sacc[mi][ni][r] = -1e30f;
            }
      }

      // ---- online softmax (rows live in 16-lane groups: reduce over fr)
#pragma unroll
      for (int mi = 0; mi < 2; ++mi)
#pragma unroll
        for (int r = 0; r < 4; ++r) {
          float tm = fmaxf(fmaxf(sacc[mi][0][r], sacc[mi][1][r]),
                           fmaxf(sacc[mi][2][r], sacc[mi][3][r]));
#pragma unroll
          for (int d = 1; d < 16; d <<= 1) tm = fmaxf(tm, __shfl_xor(tm, d, 64));
          const float mOld = Mrow[mi][r];
          const float mNew = fmaxf(mOld, tm);
          const float alpha = exp2f((mOld - mNew) * C1);
          float ps = 0.f;
#pragma unroll
          for (int ni = 0; ni < 4; ++ni) {
            const float p = exp2f((sacc[mi][ni][r] - mNew) * C1);
            sacc[mi][ni][r] = p;
            ps += p;
          }
#pragma unroll
          for (int d = 1; d < 16; d <<= 1) ps += __shfl_xor(ps, d, 64);
          Lrow[mi][r] = Lrow[mi][r] * alpha + ps;
          Mrow[mi][r] = mNew;
#pragma unroll
          for (int nd = 0; nd < 8; ++nd) oacc[mi][nd][r] *= alpha;
        }
    }

    // ---- write V(kt+1) into buf^1 (all threads; vmcnt waits here, not earlier)
    if (kt < ktmax) {
      bf16_t* vt = &lVT[(kt + 1) & 1][0];
#pragma unroll
      for (int j = 0; j < 8; ++j) {
        *(u32*)&vt[(kd0 + j) * 72 + c0] = (u32)(u16)sva0[j] | ((u32)(u16)svb0[j] << 16);
        *(u32*)&vt[(kd0 + j) * 72 + c1] = (u32)(u16)sva1[j] | ((u32)(u16)svb1[j] << 16);
      }
    }

    if (!skip) {
      // ---- P -> per-wave LDS (bf16, swizzled)
      bf16_t* lPw = &lP[w][0];
#pragma unroll
      for (int mi = 0; mi < 2; ++mi)
#pragma unroll
        for (int ni = 0; ni < 4; ++ni)
#pragma unroll
          for (int r = 0; r < 4; ++r) {
            const int ql = mi * 16 + fg * 4 + r;
            const int kl = ni * 16 + fr;
            lPw[ql * 64 + (kl ^ ((ql & 7) << 3))] = (bf16_t)sacc[mi][ni][r];
          }

      // ---- O += P V from buf[kt&1]
      const bf16_t* vt = &lVT[kt & 1][0];
#pragma unroll
      for (int ks2 = 0; ks2 < 2; ++ks2) {
        s16x8 pf[2];
#pragma unroll
        for (int mi = 0; mi < 2; ++mi) {
          const int q = mi * 16 + fr;
          pf[mi] = *(const s16x8*)&lPw[q * 64 + ((ks2 * 32 + fg * 8) ^ ((q & 7) << 3))];
        }
#pragma unroll
        for (int nd = 0; nd < 8; ++nd) {
          const int d = nd * 16 + fr;
          const s16x8 vf = *(const s16x8*)&vt[d * 72 + ((ks2 * 32 + fg * 8) ^ (((d >> 3) & 7) << 3))];
#pragma unroll
          for (int mi = 0; mi < 2; ++mi)
            oacc[mi][nd] = __builtin_amdgcn_mfma_f32_16x16x32_bf16(pf[mi], vf, oacc[mi][nd], 0, 0, 0);
        }
      }
    }
  }

  // ---- epilogue: normalize + store bf16
#pragma unroll
  for (int mi = 0; mi < 2; ++mi)
#pragma unroll
    for (int nd = 0; nd < 8; ++nd)
#pragma unroll
      for (int r = 0; r < 4; ++r) {
        const int rr = rowg0 + mi * 16 + fg * 4 + r;
        o[(size_t)(b * S + rr) * 2048 + h * 128 + nd * 16 + fr] =
            (bf16_t)(oacc[mi][nd][r] / Lrow[mi][r]);
      }
}

// ---------------------------------------------------------------- launcher
extern "C" void kernel_launch(void* const* d_in, const int* in_sizes, int n_in,
                              void* d_out, int out_size, void* d_ws, size_t ws_size,
                              hipStream_t stream) {
  (void)in_sizes; (void)n_in; (void)out_size; (void)ws_size;
  const float* x     = (const float*)d_in[0];
  const float* freqs = (const float*)d_in[1];
  // d_in[2] = mask: causal, computed analytically
  const float* wq = (const float*)d_in[3];
  const float* wk = (const float*)d_in[4];
  const float* wv = (const float*)d_in[5];
  const float* wo = (const float*)d_in[6];
  float* out = (float*)d_out;

  char* ws = (char*)d_ws;
  bf16_t* xb  = (bf16_t*)(ws);                  // [8192][2048]  33.55 MB
  bf16_t* Wb  = (bf16_t*)(ws + 33554432);       // [3072][2048]  12.58 MB
  bf16_t* wob = (bf16_t*)(ws + 46137344);       // [2048][2048]   8.39 MB
  bf16_t* qkv = (bf16_t*)(ws + 54525952);       // [8192][3072]  50.33 MB
  bf16_t* att = xb;                             // reuse x region after GEMM1

  // casts
  cast_bf16_k<<<16384, 256, 0, stream>>>(x, xb, 8192 * 2048);
  cast_bf16_k<<<4096, 256, 0, stream>>>(wq, Wb, 2048 * 2048);
  cast_bf16_k<<<1024, 256, 0, stream>>>(wk, Wb + 2048 * 2048, 512 * 2048);
  cast_bf16_k<<<1024, 256, 0, stream>>>(wv, Wb + 2560 * 2048, 512 * 2048);
  cast_bf16_k<<<4096, 256, 0, stream>>>(wo, wob, 2048 * 2048);

  // qkv = xb @ Wb^T  (M=8192, N=3072, K=2048), bf16 out
  gemm_bt<0><<<dim3(64, 24), 256, 0, stream>>>(xb, Wb, nullptr, qkv, 8192, 3072, 2048);

  // rope on q,k heads in-place: 8192 rows * 20 heads, 4 rows/block
  rope_k<<<40960, 256, 0, stream>>>(qkv, freqs);

  // attention -> att [8192][2048] bf16 (1-D grid, XCD-chunked + LPT order)
  attn_k<<<1024, 256, 0, stream>>>(qkv, att);

  // out = att @ wob^T (M=8192, N=2048, K=2048), fp32 out
  gemm_bt<1><<<dim3(64, 16), 256, 0, stream>>>(att, wob, out, nullptr, 8192, 2048, 2048);
}